// Round 6
// baseline (153.519 us; speedup 1.0000x reference)
//
#include <hip/hip_runtime.h>
#include <math.h>

typedef float f32x4 __attribute__((ext_vector_type(4)));
typedef _Float16 f16x4 __attribute__((ext_vector_type(4)));
typedef __fp16 fp16x2 __attribute__((ext_vector_type(2)));
typedef __fp16 fp16x4 __attribute__((ext_vector_type(4)));

#define MFMA_F16 __builtin_amdgcn_mfma_f32_16x16x16f16

namespace {
constexpr float DT = 0.05f;
constexpr int NSTEPS = 4;

struct Split { f16x4 h; f16x4 l; };

// 4x f32 -> packed f16x4 via v_cvt_pkrtz_f16_f32 (2 instrs)
__device__ __forceinline__ f16x4 pk4(f32x4 v) {
  fp16x2 a = __builtin_amdgcn_cvt_pkrtz(v[0], v[1]);
  fp16x2 b = __builtin_amdgcn_cvt_pkrtz(v[2], v[3]);
  fp16x4 r = __builtin_shufflevector(a, b, 0, 1, 2, 3);
  return __builtin_bit_cast(f16x4, r);
}

// full hi/lo split: hi = RTZ(x); lo = RTZ(x - hi). ~12 instrs.
__device__ __forceinline__ Split mksplit(f32x4 v) {
  Split s;
  s.h = pk4(v);
  f32x4 hf;
#pragma unroll
  for (int i = 0; i < 4; ++i) hf[i] = (float)s.h[i];
  s.l = pk4(v - hf);
  return s;
}

__device__ __forceinline__ f32x4 mm1(f16x4 ah, f16x4 bh) {
  f32x4 acc = {0.f, 0.f, 0.f, 0.f};
  acc = MFMA_F16(ah, bh, acc, 0, 0, 0);
  return acc;
}

// Layout invariant: all matrices live in the 16x16 MFMA C/D layout
// (lane holds rows 4*(lane>>4)+i at col lane&15) == B-fragment layout.
// Feeding M's C-layout regs as the A-operand computes M^T * B, so every
// A-operand below is (numerically) symmetric.
struct El {
  f32x4 Sg, Dv;   // f32 state
  Split sS, sD;   // f16 hi/lo splits of state
};

// half kick: D -= 0.5 * D*(S*D).  T = S.h*D (2 MFMA, drop S.l term),
// K accumulated straight into Dv with -0.5 folded into Th.
__device__ __forceinline__ void kick(El& E) {
  f32x4 T = {0.f, 0.f, 0.f, 0.f};
  T = MFMA_F16(E.sS.h, E.sD.h, T, 0, 0, 0);
  T = MFMA_F16(E.sS.h, E.sD.l, T, 0, 0, 0);
  f16x4 Th = pk4(-0.5f * T);
  E.Dv = MFMA_F16(E.sD.h, Th, E.Dv, 0, 0, 0);
  E.Dv = MFMA_F16(E.sD.l, Th, E.Dv, 0, 0, 0);
  E.sD = mksplit(E.Dv);
}

// drift: Sigma <- S*exp(D*S) = sum_k Z_k/k!,  Z_k = Z_{k-1}*X, X = D*S, Z_0 = S
__device__ __forceinline__ void drift(El& E) {
  f32x4 X = {0.f, 0.f, 0.f, 0.f};
  X = MFMA_F16(E.sD.h, E.sS.h, X, 0, 0, 0);
  X = MFMA_F16(E.sD.l, E.sS.h, X, 0, 0, 0);
  X = MFMA_F16(E.sD.h, E.sS.l, X, 0, 0, 0);
  Split sX = mksplit(X);
  f32x4 Z = {0.f, 0.f, 0.f, 0.f};
  Z = MFMA_F16(E.sS.h, sX.h, Z, 0, 0, 0);
  Z = MFMA_F16(E.sS.l, sX.h, Z, 0, 0, 0);
  Z = MFMA_F16(E.sS.h, sX.l, Z, 0, 0, 0);
  f32x4 ACC = E.Sg + Z;
  f16x4 zh = pk4(Z);
  Z = mm1(zh, sX.h); ACC += (1.0f / 2.0f) * Z; zh = pk4(Z);   // Z2
  Z = mm1(zh, sX.h); ACC += (1.0f / 6.0f) * Z; zh = pk4(Z);   // Z3
  Z = mm1(zh, sX.h); ACC += (1.0f / 24.0f) * Z;               // Z4
  E.Sg = ACC;
  E.sS = mksplit(ACC);
}
} // namespace

// Two elements per wave: two independent MFMA->VALU dependency chains
// interleave on the SIMD (R5: VALU 54% + MFMA 29% ran serially).
__global__ __launch_bounds__(256, 4) void ham_leapfrog(
    const float* __restrict__ mu, const float* __restrict__ Sigma,
    const float* __restrict__ phi, const float* __restrict__ pi_mu,
    const float* __restrict__ pi_Sigma, const float* __restrict__ pi_phi,
    const float* __restrict__ M_inv, float* __restrict__ out, int n_elem) {
  const int wave = threadIdx.x >> 6;
  const int lane = threadIdx.x & 63;
  const int gw = blockIdx.x * (blockDim.x >> 6) + wave;
  const int e0 = gw * 2;
  if (e0 >= n_elem) return;
  const int e1 = (e0 + 1 < n_elem) ? e0 + 1 : e0;

  const int c = lane & 15;
  const int r0 = (lane >> 4) * 4;
  const int base = r0 * 16 + c;

  // ---- load matrix state for both elements (C-layout) ----
  El E0, E1;
  f32x4 Mi0, Mi1;
#pragma unroll
  for (int j = 0; j < 4; ++j) {
    const int o0 = e0 * 256 + base + j * 16;
    const int o1 = e1 * 256 + base + j * 16;
    E0.Sg[j] = Sigma[o0];     E1.Sg[j] = Sigma[o1];
    E0.Dv[j] = pi_Sigma[o0];  E1.Dv[j] = pi_Sigma[o1];
    Mi0[j]   = M_inv[o0];     Mi1[j]   = M_inv[o1];
  }
  E0.Dv = (2.0f * DT) * E0.Dv;   // D = 2*dt*pi
  E1.Dv = (2.0f * DT) * E1.Dv;

  // ---- mu via MFMA (pi_mu embedded in column 0 of B) ----
  f32x4 pm0 = *(const f32x4*)(pi_mu + e0 * 16 + r0);
  f32x4 pm1 = *(const f32x4*)(pi_mu + e1 * 16 + r0);
  f16x4 Ph0 = pk4(pm0), Ph1 = pk4(pm1);
  if (c != 0) { Ph0 = (f16x4)(_Float16)0; Ph1 = (f16x4)(_Float16)0; }
  f32x4 am0 = mm1(pk4(Mi0), Ph0);
  f32x4 am1 = mm1(pk4(Mi1), Ph1);
  // store mu now (frees am regs before the matrix loop)
  if (c == 0) {
    f32x4 mu0 = *(const f32x4*)(mu + e0 * 16 + r0);
    f32x4 mu1 = *(const f32x4*)(mu + e1 * 16 + r0);
    *(f32x4*)(out + e0 * 16 + r0) = mu0 + ((float)NSTEPS * DT) * am0;
    *(f32x4*)(out + e1 * 16 + r0) = mu1 + ((float)NSTEPS * DT) * am1;
  }

  // ---- matrix leapfrog, two chains interleaved ----
  E0.sS = mksplit(E0.Sg);  E1.sS = mksplit(E1.Sg);
  E0.sD = mksplit(E0.Dv);  E1.sD = mksplit(E1.Dv);

#pragma unroll
  for (int step = 0; step < NSTEPS; ++step) {
    kick(E0);  kick(E1);
    drift(E0); drift(E1);
    kick(E0);  kick(E1);
  }

  // ---- Sigma stores ----
  float* out_Sg = out + (size_t)n_elem * 16;
#pragma unroll
  for (int j = 0; j < 4; ++j) {
    out_Sg[e0 * 256 + base + j * 16] = E0.Sg[j];
    out_Sg[e1 * 256 + base + j * 16] = E1.Sg[j];
  }

  // ---- phi (after matrix loop to keep registers cold during it) ----
  const float TWO_PI = 6.28318530717958647692f;
  const float INV_2PI = 0.15915494309189533577f;
  const float PI_F = 3.14159265358979323846f;
  const float R_MAX = 3.13159265358979323846f;  // pi - 0.01
  float* out_ph = out + (size_t)n_elem * (16 + 256);
  if (lane < 2) {
    const int e = (lane == 0) ? e0 : e1;
    float p0 = phi[e * 3 + 0], p1 = phi[e * 3 + 1], p2 = phi[e * 3 + 2];
    const float q0 = DT * pi_phi[e * 3 + 0];
    const float q1 = DT * pi_phi[e * 3 + 1];
    const float q2 = DT * pi_phi[e * 3 + 2];
#pragma unroll
    for (int s = 0; s < NSTEPS; ++s) {
      p0 += q0; p1 += q1; p2 += q2;
      float th = sqrtf(p0 * p0 + p1 * p1 + p2 * p2);
      float inv = __builtin_amdgcn_rcpf(fmaxf(th, 1e-12f));
      float tw = th - TWO_PI * floorf(th * INV_2PI);  // remainder, th >= 0
      bool flip = tw > PI_F;
      float tf = flip ? (TWO_PI - tw) : tw;
      float sgn = flip ? -1.f : 1.f;
      tf = fminf(tf, R_MAX);
      float f = sgn * inv * tf;
      p0 *= f; p1 *= f; p2 *= f;
    }
    out_ph[e * 3 + 0] = p0;
    out_ph[e * 3 + 1] = p1;
    out_ph[e * 3 + 2] = p2;
  }
}

extern "C" void kernel_launch(void* const* d_in, const int* in_sizes, int n_in,
                              void* d_out, int out_size, void* d_ws, size_t ws_size,
                              hipStream_t stream) {
  const float* mu       = (const float*)d_in[0];
  const float* Sigma    = (const float*)d_in[1];
  const float* phi      = (const float*)d_in[2];
  const float* pi_mu    = (const float*)d_in[3];
  const float* pi_Sigma = (const float*)d_in[4];
  const float* pi_phi   = (const float*)d_in[5];
  const float* M_inv    = (const float*)d_in[6];
  float* o = (float*)d_out;

  const int n_elem = in_sizes[0] / 16;            // B*N = 32768
  const int waves_per_block = 4;                  // 256 threads
  const int elems_per_block = waves_per_block * 2;
  const int blocks = (n_elem + elems_per_block - 1) / elems_per_block;
  hipLaunchKernelGGL(ham_leapfrog, dim3(blocks), dim3(256), 0, stream,
                     mu, Sigma, phi, pi_mu, pi_Sigma, pi_phi, M_inv, o, n_elem);
}

// Round 7
// 148.358 us; speedup vs baseline: 1.0348x; 1.0348x over previous
//
#include <hip/hip_runtime.h>
#include <math.h>

typedef float f32x4 __attribute__((ext_vector_type(4)));
typedef _Float16 f16x4 __attribute__((ext_vector_type(4)));
typedef __fp16 fp16x2 __attribute__((ext_vector_type(2)));
typedef __fp16 fp16x4 __attribute__((ext_vector_type(4)));

#define MFMA_F16 __builtin_amdgcn_mfma_f32_16x16x16f16

namespace {
constexpr float DT = 0.05f;
constexpr int NSTEPS = 4;

// 4x f32 -> packed f16x4 via v_cvt_pkrtz_f16_f32 (2 instrs)
__device__ __forceinline__ f16x4 pk4(f32x4 v) {
  fp16x2 a = __builtin_amdgcn_cvt_pkrtz(v[0], v[1]);
  fp16x2 b = __builtin_amdgcn_cvt_pkrtz(v[2], v[3]);
  fp16x4 r = __builtin_shufflevector(a, b, 0, 1, 2, 3);
  return __builtin_bit_cast(f16x4, r);
}

__device__ __forceinline__ f32x4 mm1(f16x4 ah, f16x4 bh) {
  f32x4 acc = {0.f, 0.f, 0.f, 0.f};
  acc = MFMA_F16(ah, bh, acc, 0, 0, 0);
  return acc;
}

// Layout invariant: all matrices live in the 16x16 MFMA C/D layout
// (lane holds rows 4*(lane>>4)+i at col lane&15) == B-fragment layout.
// A-operand computes M^T*B, so every A-operand is (numerically) symmetric:
// S, S.l (residual of symmetric is symmetric), D, and Z_k = S(DS)^k.
struct El {
  f32x4 Sg, Dv;        // f32 state
  f16x4 Sh, Sl, Dh;    // f16: S hi+lo, D hi-only
};

__device__ __forceinline__ void splitS(El& E) {
  E.Sh = pk4(E.Sg);
  f32x4 hf;
#pragma unroll
  for (int i = 0; i < 4; ++i) hf[i] = (float)E.Sh[i];
  E.Sl = pk4(E.Sg - hf);
}

// half kick: D -= 0.5*D*(S*D). h-only: error ~1e-5 abs on Sigma per step.
__device__ __forceinline__ void kick(El& E) {
  f32x4 T = mm1(E.Sh, E.Dh);                    // S.h * D.h
  f16x4 Th = pk4(-0.5f * T);
  E.Dv = MFMA_F16(E.Dh, Th, E.Dv, 0, 0, 0);     // Dv - 0.5*D.h*T
  E.Dh = pk4(E.Dv);
}

// drift: Sigma <- S*exp(D*S) = sum_k Z_k/k!, Z_k = Z_{k-1}*X, X = D*S, Z_0 = S.
// S.l refinement kept on X and Z1 (the two dominant error paths).
__device__ __forceinline__ void drift(El& E) {
  f32x4 X = mm1(E.Dh, E.Sh);
  X = MFMA_F16(E.Dh, E.Sl, X, 0, 0, 0);         // + D.h*S.l
  f16x4 Xh = pk4(X);
  f32x4 Z = mm1(E.Sh, Xh);
  Z = MFMA_F16(E.Sl, Xh, Z, 0, 0, 0);           // + S.l*X.h
  f32x4 ACC = E.Sg + Z;
  f16x4 zh = pk4(Z);
  Z = mm1(zh, Xh); ACC += (1.0f / 2.0f) * Z; zh = pk4(Z);   // Z2
  Z = mm1(zh, Xh); ACC += (1.0f / 6.0f) * Z; zh = pk4(Z);   // Z3
  Z = mm1(zh, Xh); ACC += (1.0f / 24.0f) * Z;               // Z4
  E.Sg = ACC;
  splitS(E);
}
} // namespace

// Two elements per wave for ILP; h-only arithmetic (R7) halves VALU+MFMA work.
__global__ __launch_bounds__(256, 4) void ham_leapfrog(
    const float* __restrict__ mu, const float* __restrict__ Sigma,
    const float* __restrict__ phi, const float* __restrict__ pi_mu,
    const float* __restrict__ pi_Sigma, const float* __restrict__ pi_phi,
    const float* __restrict__ M_inv, float* __restrict__ out, int n_elem) {
  const int wave = threadIdx.x >> 6;
  const int lane = threadIdx.x & 63;
  const int gw = blockIdx.x * (blockDim.x >> 6) + wave;
  const int e0 = gw * 2;
  if (e0 >= n_elem) return;
  const int e1 = (e0 + 1 < n_elem) ? e0 + 1 : e0;

  const int c = lane & 15;
  const int r0 = (lane >> 4) * 4;
  const int base = r0 * 16 + c;

  // ---- load matrix state for both elements (C-layout) ----
  El E0, E1;
  f32x4 Mi0, Mi1;
#pragma unroll
  for (int j = 0; j < 4; ++j) {
    const int o0 = e0 * 256 + base + j * 16;
    const int o1 = e1 * 256 + base + j * 16;
    E0.Sg[j] = Sigma[o0];     E1.Sg[j] = Sigma[o1];
    E0.Dv[j] = pi_Sigma[o0];  E1.Dv[j] = pi_Sigma[o1];
    Mi0[j]   = M_inv[o0];     Mi1[j]   = M_inv[o1];
  }
  E0.Dv = (2.0f * DT) * E0.Dv;   // D = 2*dt*pi
  E1.Dv = (2.0f * DT) * E1.Dv;

  // ---- mu via MFMA (pi_mu embedded in column 0 of B) ----
  f32x4 pm0 = *(const f32x4*)(pi_mu + e0 * 16 + r0);
  f32x4 pm1 = *(const f32x4*)(pi_mu + e1 * 16 + r0);
  f16x4 Ph0 = pk4(pm0), Ph1 = pk4(pm1);
  if (c != 0) { Ph0 = (f16x4)(_Float16)0; Ph1 = (f16x4)(_Float16)0; }
  f32x4 am0 = mm1(pk4(Mi0), Ph0);
  f32x4 am1 = mm1(pk4(Mi1), Ph1);
  if (c == 0) {
    f32x4 mu0 = *(const f32x4*)(mu + e0 * 16 + r0);
    f32x4 mu1 = *(const f32x4*)(mu + e1 * 16 + r0);
    *(f32x4*)(out + e0 * 16 + r0) = mu0 + ((float)NSTEPS * DT) * am0;
    *(f32x4*)(out + e1 * 16 + r0) = mu1 + ((float)NSTEPS * DT) * am1;
  }

  // ---- matrix leapfrog, two chains interleaved ----
  splitS(E0);  splitS(E1);
  E0.Dh = pk4(E0.Dv);  E1.Dh = pk4(E1.Dv);

#pragma unroll
  for (int step = 0; step < NSTEPS; ++step) {
    kick(E0);  kick(E1);
    drift(E0); drift(E1);
    kick(E0);  kick(E1);
  }

  // ---- Sigma stores ----
  float* out_Sg = out + (size_t)n_elem * 16;
#pragma unroll
  for (int j = 0; j < 4; ++j) {
    out_Sg[e0 * 256 + base + j * 16] = E0.Sg[j];
    out_Sg[e1 * 256 + base + j * 16] = E1.Sg[j];
  }

  // ---- phi (tiny, divergent tail) ----
  const float TWO_PI = 6.28318530717958647692f;
  const float INV_2PI = 0.15915494309189533577f;
  const float PI_F = 3.14159265358979323846f;
  const float R_MAX = 3.13159265358979323846f;  // pi - 0.01
  float* out_ph = out + (size_t)n_elem * (16 + 256);
  if (lane < 2) {
    const int e = (lane == 0) ? e0 : e1;
    float p0 = phi[e * 3 + 0], p1 = phi[e * 3 + 1], p2 = phi[e * 3 + 2];
    const float q0 = DT * pi_phi[e * 3 + 0];
    const float q1 = DT * pi_phi[e * 3 + 1];
    const float q2 = DT * pi_phi[e * 3 + 2];
#pragma unroll
    for (int s = 0; s < NSTEPS; ++s) {
      p0 += q0; p1 += q1; p2 += q2;
      float th = sqrtf(p0 * p0 + p1 * p1 + p2 * p2);
      float inv = __builtin_amdgcn_rcpf(fmaxf(th, 1e-12f));
      float tw = th - TWO_PI * floorf(th * INV_2PI);  // remainder, th >= 0
      bool flip = tw > PI_F;
      float tf = flip ? (TWO_PI - tw) : tw;
      float sgn = flip ? -1.f : 1.f;
      tf = fminf(tf, R_MAX);
      float f = sgn * inv * tf;
      p0 *= f; p1 *= f; p2 *= f;
    }
    out_ph[e * 3 + 0] = p0;
    out_ph[e * 3 + 1] = p1;
    out_ph[e * 3 + 2] = p2;
  }
}

extern "C" void kernel_launch(void* const* d_in, const int* in_sizes, int n_in,
                              void* d_out, int out_size, void* d_ws, size_t ws_size,
                              hipStream_t stream) {
  const float* mu       = (const float*)d_in[0];
  const float* Sigma    = (const float*)d_in[1];
  const float* phi      = (const float*)d_in[2];
  const float* pi_mu    = (const float*)d_in[3];
  const float* pi_Sigma = (const float*)d_in[4];
  const float* pi_phi   = (const float*)d_in[5];
  const float* M_inv    = (const float*)d_in[6];
  float* o = (float*)d_out;

  const int n_elem = in_sizes[0] / 16;            // B*N = 32768
  const int waves_per_block = 4;                  // 256 threads
  const int elems_per_block = waves_per_block * 2;
  const int blocks = (n_elem + elems_per_block - 1) / elems_per_block;
  hipLaunchKernelGGL(ham_leapfrog, dim3(blocks), dim3(256), 0, stream,
                     mu, Sigma, phi, pi_mu, pi_Sigma, pi_phi, M_inv, o, n_elem);
}